// Round 4
// baseline (734.007 us; speedup 1.0000x reference)
//
#include <hip/hip_runtime.h>
#include <hip/hip_bf16.h>
#include <math.h>

typedef __attribute__((ext_vector_type(8))) short short8;   // 8 bf16 (4 VGPRs)
typedef __attribute__((ext_vector_type(4))) float f32x4;    // MFMA C/D

namespace {
constexpr int E_TOTAL = 500000;
constexpr int ND  = 128;   // node dim
constexpr int ED  = 64;    // edge dim
constexpr int KIN = 320;   // 2*ND + ED
constexpr int H   = 128;   // hidden
constexpr int ME  = 32;    // edges per block (500000 = 32 * 15625 -> no tail, no clamps)
constexpr int RS  = 328;   // catA row stride (shorts): 656B = 16B-aligned, +4-bank skew
constexpr float EPS = 1e-5f;
// d_ws offsets (in shorts): weights transposed [n][k], bf16
constexpr int OFF_W1T = 0;       // [128][320]
constexpr int OFF_WGT = 40960;   // [128][320]
constexpr int OFF_W2T = 81920;   // [128][128]
constexpr int OFF_WRT = 98304;   // [128][64]
}

__device__ __forceinline__ unsigned short f2bf(float f) {
  union { __hip_bfloat16 h; unsigned short u; } cv;
  cv.h = __float2bfloat16(f);   // RNE
  return cv.u;
}
__device__ __forceinline__ unsigned pack2(float a, float b) {
  return (unsigned)f2bf(a) | ((unsigned)f2bf(b) << 16);
}

// exact GELU via branch-free Abramowitz-Stegun 7.1.26 erf (|err| <= 1.5e-7).
// ~16 VALU ops, no divergence. Verified win (rounds 1-3).
__device__ __forceinline__ float gelu_erf(float x) {
  const float s = x * 0.70710678118654752f;
  const float a = fabsf(s);
  const float t = __builtin_amdgcn_rcpf(fmaf(0.3275911f, a, 1.0f));
  float p = fmaf(1.061405429f, t, -1.453152027f);
  p = fmaf(p, t, 1.421413741f);
  p = fmaf(p, t, -0.284496736f);
  p = fmaf(p, t, 0.254829592f);
  p = p * t;
  const float e = __expf(-a * a);
  float er = fmaf(-p, e, 1.0f);          // erf(|s|)
  er = copysignf(er, s);
  return 0.5f * x * (1.0f + er);
}

// One-shot (per launch) weight prep: fp32 [K][N] -> bf16 transposed [N][K] in ws.
__global__ void prep_weights(const float* __restrict__ W1, const float* __restrict__ Wg,
                             const float* __restrict__ W2, const float* __restrict__ Wr,
                             short* __restrict__ wt) {
  const int t = blockIdx.x * 256 + threadIdx.x;
  if (t < 40960) {                       // W1T / WgT: n in [0,128), k in [0,320)
    const int n = t / KIN, k = t % KIN;
    wt[OFF_W1T + t] = (short)f2bf(W1[k * H + n]);
    wt[OFF_WGT + t] = (short)f2bf(Wg[k * H + n]);
  }
  if (t < 16384) {                       // W2T: [128][128]
    const int n = t / H, k = t % H;
    wt[OFF_W2T + t] = (short)f2bf(W2[k * H + n]);
  }
  if (t < 8192) {                        // WrT: [128][64]
    const int n = t / ED, k = t % ED;
    wt[OFF_WRT + t] = (short)f2bf(Wr[k * H + n]);
  }
}

// Block: 256 threads = 4 waves, 32 edges (2 M-tiles). Wave w owns cols [32w, 32w+32)
// (2 N-tiles) for BOTH M-tiles. vs the 64-edge version: accumulator footprint halves
// (64 -> 32 regs at peak; unified ~108/wave), LDS halves (22.3 KB), every serial
// per-thread phase halves (gather 10 float4 loads, 16 GELUs, 16 stores) -> 4-5
// resident blocks/CU instead of 3, better cross-block phase overlap.
// REGISTER LESSON (r1-r2): never force a cap into the estimated-fit zone; (256,3)
// caps at 170 (slack), natural alloc ~110 gives 4 waves/SIMD by itself.
// Cost accepted: 2x weight B-frag re-reads per edge — wt (213 KB) is L2-resident.
__global__ __launch_bounds__(256, 3) void edge_mfma_kernel(
    const float* __restrict__ x, const int* __restrict__ ei, const float* __restrict__ ea,
    const short* __restrict__ wt,
    const float* __restrict__ b1, const float* __restrict__ g1, const float* __restrict__ be1,
    const float* __restrict__ b2, const float* __restrict__ bg, const float* __restrict__ br,
    const float* __restrict__ g2, const float* __restrict__ be2,
    float* __restrict__ out)
{
  __shared__ short catA[ME * RS];   // 20992 B
  __shared__ float red[ME][8];      // per-row {s,q} x 4 waves  (1024 B)
  __shared__ int   sidx[ME], didx[ME];

  const int t    = threadIdx.x;
  const int w    = t >> 6;
  const int lane = t & 63;
  const int g    = lane >> 4;   // quad
  const int l15  = lane & 15;
  const long e0  = (long)blockIdx.x * ME;   // always < E_TOTAL, exact division

  if (t < ME) {
    sidx[t] = ei[e0 + t];
  } else if (t < 2 * ME) {
    didx[t - ME] = ei[E_TOTAL + e0 + (t - ME)];
  }
  __syncthreads();

  // ---- gather: catA[e][k] = bf16([x[src] | x[dst] | ea]) ; float4 loads ----
  {
    const int e8 = t >> 5;               // 0..7
    const int c  = (t & 31) << 2;        // 0,4,...,124
    #pragma unroll
    for (int i = 0; i < 4; ++i) {
      const int e = i * 8 + e8;
      const float4 xs = *(const float4*)(x + (long)sidx[e] * ND + c);
      const float4 xd = *(const float4*)(x + (long)didx[e] * ND + c);
      uint2 ps, pd;
      ps.x = pack2(xs.x, xs.y); ps.y = pack2(xs.z, xs.w);
      pd.x = pack2(xd.x, xd.y); pd.y = pack2(xd.z, xd.w);
      *(uint2*)&catA[e * RS + c]      = ps;
      *(uint2*)&catA[e * RS + ND + c] = pd;
    }
    const int e16 = t >> 4;              // 0..15
    const int c2  = (t & 15) << 2;       // 0,4,...,60
    #pragma unroll
    for (int i = 0; i < 2; ++i) {
      const int e = i * 16 + e16;
      const float4 v = *(const float4*)(ea + (e0 + e) * ED + c2);
      uint2 pe;
      pe.x = pack2(v.x, v.y); pe.y = pack2(v.z, v.w);
      *(uint2*)&catA[e * RS + 2 * ND + c2] = pe;
    }
  }
  __syncthreads();

  const int col0 = w * 32 + l15;        // N-tile 0 col
  const int col1 = w * 32 + 16 + l15;   // N-tile 1 col

  // ---- GEMM1: h_pre = cat@W1 + b1 ; g_pre = cat@Wg + bg ----
  f32x4 accH[2][2], accG[2][2];
  {
    const float bh0 = b1[col0], bh1 = b1[col1];
    const float bg0 = bg[col0], bg1 = bg[col1];
    #pragma unroll
    for (int mt = 0; mt < 2; ++mt) {
      accH[mt][0] = (f32x4){bh0, bh0, bh0, bh0};
      accH[mt][1] = (f32x4){bh1, bh1, bh1, bh1};
      accG[mt][0] = (f32x4){bg0, bg0, bg0, bg0};
      accG[mt][1] = (f32x4){bg1, bg1, bg1, bg1};
    }
  }
  {
    const short* pW1a = wt + OFF_W1T + col0 * KIN + g * 8;
    const short* pW1b = wt + OFF_W1T + col1 * KIN + g * 8;
    const short* pWga = wt + OFF_WGT + col0 * KIN + g * 8;
    const short* pWgb = wt + OFF_WGT + col1 * KIN + g * 8;
    for (int ks = 0; ks < KIN / 32; ++ks) {
      const int ko = ks * 32 + g * 8;
      short8 a[2];
      #pragma unroll
      for (int mt = 0; mt < 2; ++mt)
        a[mt] = *(const short8*)&catA[(mt * 16 + l15) * RS + ko];
      const short8 bW1a = *(const short8*)(pW1a + ks * 32);
      const short8 bW1b = *(const short8*)(pW1b + ks * 32);
      const short8 bWga = *(const short8*)(pWga + ks * 32);
      const short8 bWgb = *(const short8*)(pWgb + ks * 32);
      #pragma unroll
      for (int mt = 0; mt < 2; ++mt) {
        accH[mt][0] = __builtin_amdgcn_mfma_f32_16x16x32_bf16(a[mt], bW1a, accH[mt][0], 0, 0, 0);
        accH[mt][1] = __builtin_amdgcn_mfma_f32_16x16x32_bf16(a[mt], bW1b, accH[mt][1], 0, 0, 0);
        accG[mt][0] = __builtin_amdgcn_mfma_f32_16x16x32_bf16(a[mt], bWga, accG[mt][0], 0, 0, 0);
        accG[mt][1] = __builtin_amdgcn_mfma_f32_16x16x32_bf16(a[mt], bWgb, accG[mt][1], 0, 0, 0);
      }
    }
  }

  // ---- LN1 stats: rows r = mt*16 + g*4 + reg; reduce wave's 32 cols then cross-wave ----
  #pragma unroll
  for (int mt = 0; mt < 2; ++mt) {
    f32x4 ps = accH[mt][0] + accH[mt][1];
    f32x4 pq = accH[mt][0] * accH[mt][0] + accH[mt][1] * accH[mt][1];
    #pragma unroll
    for (int off = 1; off < 16; off <<= 1) {
      #pragma unroll
      for (int r = 0; r < 4; ++r) {
        ps[r] += __shfl_xor(ps[r], off);
        pq[r] += __shfl_xor(pq[r], off);
      }
    }
    if (l15 == 0) {
      #pragma unroll
      for (int r = 0; r < 4; ++r) {
        red[mt * 16 + g * 4 + r][w * 2]     = ps[r];
        red[mt * 16 + g * 4 + r][w * 2 + 1] = pq[r];
      }
    }
  }
  __syncthreads();   // B1 — also orders all GEMM1 catA reads before h overwrite

  // ---- LN1 apply + exact GELU -> h to LDS (alias x[src] rows); sigmoid gate in regs ----
  {
    const float g1v0 = g1[col0], g1v1 = g1[col1];
    const float be10 = be1[col0], be11 = be1[col1];
    #pragma unroll
    for (int mt = 0; mt < 2; ++mt) {
      #pragma unroll
      for (int r = 0; r < 4; ++r) {
        const int row = mt * 16 + g * 4 + r;
        const float4 ra = *(const float4*)&red[row][0];
        const float4 rb = *(const float4*)&red[row][4];
        const float sum = ra.x + ra.z + rb.x + rb.z;
        const float sq  = ra.y + ra.w + rb.y + rb.w;
        const float m   = sum * (1.0f / H);
        float var = sq * (1.0f / H) - m * m;
        var = fmaxf(var, 0.0f);
        const float rs = __builtin_amdgcn_rsqf(var + EPS);
        float h0 = (accH[mt][0][r] - m) * rs * g1v0 + be10;
        float h1 = (accH[mt][1][r] - m) * rs * g1v1 + be11;
        h0 = gelu_erf(h0);
        h1 = gelu_erf(h1);
        catA[row * RS + col0] = (short)f2bf(h0);
        catA[row * RS + col1] = (short)f2bf(h1);
        accG[mt][0][r] = __builtin_amdgcn_rcpf(1.0f + __expf(-accG[mt][0][r]));
        accG[mt][1][r] = __builtin_amdgcn_rcpf(1.0f + __expf(-accG[mt][1][r]));
      }
    }
  }
  __syncthreads();   // B2

  // ---- GEMM2: U = h@W2 + b2 ; gate in place ; accumulate R = ea@Wr into gated U ----
  f32x4 accU[2][2];
  {
    const float bu0 = b2[col0], bu1 = b2[col1];
    #pragma unroll
    for (int mt = 0; mt < 2; ++mt) {
      accU[mt][0] = (f32x4){bu0, bu0, bu0, bu0};
      accU[mt][1] = (f32x4){bu1, bu1, bu1, bu1};
    }
  }
  {
    const short* pW2a = wt + OFF_W2T + col0 * H + g * 8;
    const short* pW2b = wt + OFF_W2T + col1 * H + g * 8;
    for (int ks = 0; ks < H / 32; ++ks) {
      const int ko = ks * 32 + g * 8;
      short8 a[2];
      #pragma unroll
      for (int mt = 0; mt < 2; ++mt)
        a[mt] = *(const short8*)&catA[(mt * 16 + l15) * RS + ko];
      const short8 b0  = *(const short8*)(pW2a + ks * 32);
      const short8 b1v = *(const short8*)(pW2b + ks * 32);
      #pragma unroll
      for (int mt = 0; mt < 2; ++mt) {
        accU[mt][0] = __builtin_amdgcn_mfma_f32_16x16x32_bf16(a[mt], b0,  accU[mt][0], 0, 0, 0);
        accU[mt][1] = __builtin_amdgcn_mfma_f32_16x16x32_bf16(a[mt], b1v, accU[mt][1], 0, 0, 0);
      }
    }
  }
  // gate in place: accU = U*sigmoid + br ; accG dies here (frees 16 acc regs)
  {
    const float br0 = br[col0], br1 = br[col1];
    const f32x4 vbr0 = (f32x4){br0, br0, br0, br0};
    const f32x4 vbr1 = (f32x4){br1, br1, br1, br1};
    #pragma unroll
    for (int mt = 0; mt < 2; ++mt) {
      accU[mt][0] = accU[mt][0] * accG[mt][0] + vbr0;
      accU[mt][1] = accU[mt][1] * accG[mt][1] + vbr1;
    }
  }
  // R part: ea@Wr accumulated via MFMA C-in (ea rows staged in catA cols 256..320)
  {
    const short* pWra = wt + OFF_WRT + col0 * ED + g * 8;
    const short* pWrb = wt + OFF_WRT + col1 * ED + g * 8;
    #pragma unroll
    for (int ks = 0; ks < 2; ++ks) {
      const int ko = 2 * ND + ks * 32 + g * 8;
      short8 a[2];
      #pragma unroll
      for (int mt = 0; mt < 2; ++mt)
        a[mt] = *(const short8*)&catA[(mt * 16 + l15) * RS + ko];
      const short8 b0  = *(const short8*)(pWra + ks * 32);
      const short8 b1v = *(const short8*)(pWrb + ks * 32);
      #pragma unroll
      for (int mt = 0; mt < 2; ++mt) {
        accU[mt][0] = __builtin_amdgcn_mfma_f32_16x16x32_bf16(a[mt], b0,  accU[mt][0], 0, 0, 0);
        accU[mt][1] = __builtin_amdgcn_mfma_f32_16x16x32_bf16(a[mt], b1v, accU[mt][1], 0, 0, 0);
      }
    }
  }

  // ---- LN2 ----
  #pragma unroll
  for (int mt = 0; mt < 2; ++mt) {
    f32x4 ps = accU[mt][0] + accU[mt][1];
    f32x4 pq = accU[mt][0] * accU[mt][0] + accU[mt][1] * accU[mt][1];
    #pragma unroll
    for (int off = 1; off < 16; off <<= 1) {
      #pragma unroll
      for (int r = 0; r < 4; ++r) {
        ps[r] += __shfl_xor(ps[r], off);
        pq[r] += __shfl_xor(pq[r], off);
      }
    }
    if (l15 == 0) {
      #pragma unroll
      for (int r = 0; r < 4; ++r) {
        red[mt * 16 + g * 4 + r][w * 2]     = ps[r];
        red[mt * 16 + g * 4 + r][w * 2 + 1] = pq[r];
      }
    }
  }
  __syncthreads();   // B3
  {
    const float g2v0 = g2[col0], g2v1 = g2[col1];
    const float be20 = be2[col0], be21 = be2[col1];
    #pragma unroll
    for (int mt = 0; mt < 2; ++mt) {
      #pragma unroll
      for (int r = 0; r < 4; ++r) {
        const int row = mt * 16 + g * 4 + r;
        const float4 ra = *(const float4*)&red[row][0];
        const float4 rb = *(const float4*)&red[row][4];
        const float sum = ra.x + ra.z + rb.x + rb.z;
        const float sq  = ra.y + ra.w + rb.y + rb.w;
        const float m   = sum * (1.0f / H);
        float var = sq * (1.0f / H) - m * m;
        var = fmaxf(var, 0.0f);
        const float rs = __builtin_amdgcn_rsqf(var + EPS);
        const long eg = e0 + row;
        out[eg * H + col0] = (accU[mt][0][r] - m) * rs * g2v0 + be20;
        out[eg * H + col1] = (accU[mt][1][r] - m) * rs * g2v1 + be21;
      }
    }
  }
}

extern "C" void kernel_launch(void* const* d_in, const int* in_sizes, int n_in,
                              void* d_out, int out_size, void* d_ws, size_t ws_size,
                              hipStream_t stream) {
  const float* x   = (const float*)d_in[0];
  const int*   ei  = (const int*)  d_in[1];
  const float* ea  = (const float*)d_in[2];
  const float* W1  = (const float*)d_in[3];
  const float* b1  = (const float*)d_in[4];
  const float* g1  = (const float*)d_in[5];
  const float* be1 = (const float*)d_in[6];
  const float* W2  = (const float*)d_in[7];
  const float* b2  = (const float*)d_in[8];
  const float* Wg  = (const float*)d_in[9];
  const float* bg  = (const float*)d_in[10];
  const float* Wr  = (const float*)d_in[11];
  const float* br  = (const float*)d_in[12];
  const float* g2  = (const float*)d_in[13];
  const float* be2 = (const float*)d_in[14];
  float* out = (float*)d_out;
  short* wt  = (short*)d_ws;   // 212992 B used

  prep_weights<<<160, 256, 0, stream>>>(W1, Wg, W2, Wr, wt);

  const int grid = E_TOTAL / ME;   // 15625, exact
  edge_mfma_kernel<<<grid, 256, 0, stream>>>(
      x, ei, ea, wt, b1, g1, be1, b2, bg, br, g2, be2, out);
}